// Round 3
// baseline (162.053 us; speedup 1.0000x reference)
//
#include <hip/hip_runtime.h>

#define B_DIM 512
#define F_DIM 128
#define L_DIM 1024
#define K_CLS 8
#define EPS 1e-5f
#define NROWS (B_DIM * F_DIM)          // 65536

typedef float vf4 __attribute__((ext_vector_type(4)));

// ws layout (floats):
//   [0, NROWS)            per-row sum
//   [NROWS, 2*NROWS)      per-row sumsq
//   [2*NROWS, 2*NROWS+1024)        scale[k*F+f]
//   [2*NROWS+1024, 2*NROWS+2048)   shift[k*F+f]
#define WS_S2    NROWS
#define WS_SCALE (2 * NROWS)
#define WS_SHIFT (2 * NROWS + K_CLS * F_DIM)

// Kernel 1: per-(b,f)-row sums. One wave (64 lanes) per row of L=1024 floats.
// No atomics, no pre-zeroing: each row writes its own partial slot.
__global__ __launch_bounds__(256) void cbn_stats(const float* __restrict__ x,
                                                 float* __restrict__ ws) {
    const int wave = threadIdx.x >> 6;         // 0..3
    const int lane = threadIdx.x & 63;
    const int row  = blockIdx.x * 4 + wave;    // [0, NROWS)

    const vf4* x4 = reinterpret_cast<const vf4*>(x) + (size_t)row * (L_DIM / 4);

    float s = 0.f, s2 = 0.f;
#pragma unroll
    for (int i = 0; i < 4; ++i) {
        vf4 v = x4[i * 64 + lane];
        s  += v.x + v.y + v.z + v.w;
        s2 += v.x * v.x + v.y * v.y + v.z * v.z + v.w * v.w;
    }
#pragma unroll
    for (int m = 32; m >= 1; m >>= 1) {
        s  += __shfl_xor(s, m);
        s2 += __shfl_xor(s2, m);
    }
    if (lane == 0) {
        ws[row]         = s;
        ws[WS_S2 + row] = s2;
    }
}

// Kernel 2: reduce per-row partials over the batch per class; emit scale/shift.
// One block, 1024 threads: t = k*F + f.
__global__ __launch_bounds__(1024) void cbn_finalize(const int* __restrict__ labels,
                                                     const float* __restrict__ weight,
                                                     const float* __restrict__ bias,
                                                     float* __restrict__ ws) {
    __shared__ int lbl[B_DIM];
    __shared__ int cnt[K_CLS];
    const int t = threadIdx.x;
    if (t < K_CLS) cnt[t] = 0;
    __syncthreads();
    if (t < B_DIM) {
        const int k = labels[t];
        lbl[t] = k;
        atomicAdd(&cnt[k], 1);
    }
    __syncthreads();

    const int k = t >> 7;           // / F_DIM
    const int f = t & (F_DIM - 1);

    float sum = 0.f, sumsq = 0.f;
#pragma unroll 4
    for (int b = 0; b < B_DIM; ++b) {
        const bool sel = (lbl[b] == k);
        const float ps  = ws[b * F_DIM + f];
        const float ps2 = ws[WS_S2 + b * F_DIM + f];
        sum   += sel ? ps  : 0.f;
        sumsq += sel ? ps2 : 0.f;
    }

    const float c = fmaxf((float)cnt[k] * (float)L_DIM, 1.0f);
    const float mean = sum / c;
    const float var  = sumsq / c - mean * mean;
    const float inv  = rsqrtf(var + EPS);
    const float sc   = inv * weight[t];
    ws[WS_SCALE + t] = sc;
    ws[WS_SHIFT + t] = bias[t] - mean * sc;
}

// Kernel 3: apply, traversed BACKWARD so the tail of x (freshest in L3 after
// cbn_stats' forward sweep) is read first. Non-temporal y stores avoid
// evicting x from L3. 8 row-aligned iterations per block -> row is
// block-uniform (scalar label/scale/shift loads).
#define APPLY_ITERS 8
__global__ __launch_bounds__(256) void cbn_apply(const float* __restrict__ x,
                                                 const int* __restrict__ labels,
                                                 const float* __restrict__ ws,
                                                 float* __restrict__ y) {
    const int nChunks = (int)((size_t)B_DIM * F_DIM * L_DIM / 4 / (APPLY_ITERS * 256));
    const int chunk = nChunks - 1 - blockIdx.x;           // reversed
    const size_t base = (size_t)chunk * (APPLY_ITERS * 256);

#pragma unroll
    for (int it = 0; it < APPLY_ITERS; ++it) {
        const size_t rowbase = base + (size_t)it * 256;   // row-aligned (256 f4/row)
        const int row = (int)(rowbase >> 8);              // block-uniform
        const int b = row >> 7;
        const int f = row & (F_DIM - 1);
        const int k = labels[b];
        const float sc = ws[WS_SCALE + k * F_DIM + f];
        const float sh = ws[WS_SHIFT + k * F_DIM + f];

        const size_t i4 = rowbase + threadIdx.x;
        vf4 v = reinterpret_cast<const vf4*>(x)[i4];
        vf4 o;
        o.x = v.x * sc + sh;
        o.y = v.y * sc + sh;
        o.z = v.z * sc + sh;
        o.w = v.w * sc + sh;
        __builtin_nontemporal_store(o, &reinterpret_cast<vf4*>(y)[i4]);
    }
}

extern "C" void kernel_launch(void* const* d_in, const int* in_sizes, int n_in,
                              void* d_out, int out_size, void* d_ws, size_t ws_size,
                              hipStream_t stream) {
    const float* x      = (const float*)d_in[0];
    const int*   labels = (const int*)d_in[1];
    const float* weight = (const float*)d_in[2];
    const float* bias   = (const float*)d_in[3];
    float* y  = (float*)d_out;
    float* ws = (float*)d_ws;

    cbn_stats<<<NROWS / 4, 256, 0, stream>>>(x, ws);
    cbn_finalize<<<1, 1024, 0, stream>>>(labels, weight, bias, ws);

    const int nChunks = (int)((size_t)B_DIM * F_DIM * L_DIM / 4 / (APPLY_ITERS * 256));
    cbn_apply<<<nChunks, 256, 0, stream>>>(x, labels, ws, y);
}

// Round 4
// 133.423 us; speedup vs baseline: 1.2146x; 1.2146x over previous
//
#include <hip/hip_runtime.h>

#define B_DIM 512
#define F_DIM 128
#define L_DIM 1024
#define K_CLS 8
#define EPS 1e-5f
#define NROWS (B_DIM * F_DIM)          // 65536

typedef float vf4 __attribute__((ext_vector_type(4)));

// ws layout (floats): [0, K*F) sum | [K*F, 2K*F) sumsq | [2K*F,3K*F) scale | [3K*F,4K*F) shift
#define WS_S2    (K_CLS * F_DIM)
#define WS_SCALE (2 * K_CLS * F_DIM)
#define WS_SHIFT (3 * K_CLS * F_DIM)

// Kernel 1: per-(b,f)-row sums, one wave per row, atomicAdd into [K][F].
__global__ __launch_bounds__(256) void cbn_stats(const float* __restrict__ x,
                                                 const int* __restrict__ labels,
                                                 float* __restrict__ ws) {
    const int wave = threadIdx.x >> 6;
    const int lane = threadIdx.x & 63;
    const int row  = blockIdx.x * 4 + wave;    // [0, NROWS)
    const int b = row >> 7;
    const int f = row & (F_DIM - 1);

    const vf4* x4 = reinterpret_cast<const vf4*>(x) + (size_t)row * (L_DIM / 4);

    float s = 0.f, s2 = 0.f;
#pragma unroll
    for (int i = 0; i < 4; ++i) {
        vf4 v = x4[i * 64 + lane];
        s  += v.x + v.y + v.z + v.w;
        s2 += v.x * v.x + v.y * v.y + v.z * v.z + v.w * v.w;
    }
#pragma unroll
    for (int m = 32; m >= 1; m >>= 1) {
        s  += __shfl_xor(s, m);
        s2 += __shfl_xor(s2, m);
    }
    if (lane == 0) {
        const int k = labels[b];
        atomicAdd(&ws[k * F_DIM + f], s);
        atomicAdd(&ws[WS_S2 + k * F_DIM + f], s2);
    }
}

// Kernel 2: trivial finalize — one block, 1024 threads (= K*F).
__global__ __launch_bounds__(1024) void cbn_finalize(const int* __restrict__ labels,
                                                     const float* __restrict__ weight,
                                                     const float* __restrict__ bias,
                                                     float* __restrict__ ws) {
    __shared__ int cnt[K_CLS];
    const int t = threadIdx.x;
    if (t < K_CLS) cnt[t] = 0;
    __syncthreads();
    if (t < B_DIM) atomicAdd(&cnt[labels[t]], 1);
    __syncthreads();

    const int k = t >> 7;
    const float c = fmaxf((float)cnt[k] * (float)L_DIM, 1.0f);
    const float sum   = ws[t];
    const float sumsq = ws[WS_S2 + t];
    const float mean = sum / c;
    const float var  = sumsq / c - mean * mean;
    const float inv  = rsqrtf(var + EPS);
    const float sc   = inv * weight[t];
    ws[WS_SCALE + t] = sc;
    ws[WS_SHIFT + t] = bias[t] - mean * sc;
}

// Kernel 3: apply, backward traversal, non-temporal y stores.
// 4 rows per block (256 threads = 1 row of 256 float4 per iteration).
#define APPLY_ROWS 4
__global__ __launch_bounds__(256) void cbn_apply(const float* __restrict__ x,
                                                 const int* __restrict__ labels,
                                                 const float* __restrict__ ws,
                                                 float* __restrict__ y) {
    const int nBlocks = NROWS / APPLY_ROWS;
    const int blk = nBlocks - 1 - blockIdx.x;             // reversed
    const int row0 = blk * APPLY_ROWS;

#pragma unroll
    for (int it = 0; it < APPLY_ROWS; ++it) {
        const int row = row0 + it;                        // block-uniform
        const int b = row >> 7;
        const int f = row & (F_DIM - 1);
        const int k = labels[b];
        const float sc = ws[WS_SCALE + k * F_DIM + f];
        const float sh = ws[WS_SHIFT + k * F_DIM + f];

        const size_t i4 = (size_t)row * (L_DIM / 4) + threadIdx.x;
        vf4 v = reinterpret_cast<const vf4*>(x)[i4];
        vf4 o;
        o.x = v.x * sc + sh;
        o.y = v.y * sc + sh;
        o.z = v.z * sc + sh;
        o.w = v.w * sc + sh;
        __builtin_nontemporal_store(o, &reinterpret_cast<vf4*>(y)[i4]);
    }
}

extern "C" void kernel_launch(void* const* d_in, const int* in_sizes, int n_in,
                              void* d_out, int out_size, void* d_ws, size_t ws_size,
                              hipStream_t stream) {
    const float* x      = (const float*)d_in[0];
    const int*   labels = (const int*)d_in[1];
    const float* weight = (const float*)d_in[2];
    const float* bias   = (const float*)d_in[3];
    float* y  = (float*)d_out;
    float* ws = (float*)d_ws;

    hipMemsetAsync(ws, 0, 2 * K_CLS * F_DIM * sizeof(float), stream);

    cbn_stats<<<NROWS / 4, 256, 0, stream>>>(x, labels, ws);
    cbn_finalize<<<1, 1024, 0, stream>>>(labels, weight, bias, ws);
    cbn_apply<<<NROWS / APPLY_ROWS, 256, 0, stream>>>(x, labels, ws, y);
}